// Round 10
// baseline (127.120 us; speedup 1.0000x reference)
//
#include <hip/hip_runtime.h>
#include <hip/hip_bf16.h>
#include <float.h>

// FactoredQuantizer: B=8192, M=16, N=256, C=64
// inputs  [B, M, C] fp32;  codebook [M, N, C] fp32
// out = codes [B, M, C] fp32 ++ idx [B, M] (as fp32 values)
//
// Round 19: recovery to the r17 structure (best: total 105.0 us) + keep
// ONLY r18's safe change. r18's afr-build hoist held 48 VGPRs across the
// transcode -> partial spill (+14 MB WRITE) + alloca-to-LDS (+32 KB) ->
// regression. Reverted: A-fragments are built AFTER the barrier again.
// Kept: float4-vectorized gather epilogue (8 wave-instructions instead of
// 32 scalar {shfl -> 4B load -> 4B store} chains; placed after the hot
// loop where bic[] is live anyway -> zero added register pressure).
// Same MFMA chain order, c2 summation order, tie rules -> bit-identical.

#define BQ 8192
#define MQ 16
#define NQ 256
#define CQ 64
#define RPB 512       // rows per block (16 waves x 32 rows)

typedef short  shortx8 __attribute__((ext_vector_type(8)));
typedef float  f32x4   __attribute__((ext_vector_type(4)));

#define HI_MASK 0xffff0000u

// Truncation 3-split of two floats a,b packed into three dwords
// (low short = a's bf16, high short = b's bf16). Exact: a0+a1+a2 == a.
__device__ __forceinline__ void split3_pair(float a, float b,
                                            uint& q0, uint& q1, uint& q2) {
    const uint ba = __builtin_bit_cast(uint, a);
    const uint bb = __builtin_bit_cast(uint, b);
    q0 = (ba >> 16) | (bb & HI_MASK);
    const float r1a = a - __builtin_bit_cast(float, ba & HI_MASK);
    const float r1b = b - __builtin_bit_cast(float, bb & HI_MASK);
    const uint c1a = __builtin_bit_cast(uint, r1a);
    const uint c1b = __builtin_bit_cast(uint, r1b);
    q1 = (c1a >> 16) | (c1b & HI_MASK);
    const float r2a = r1a - __builtin_bit_cast(float, c1a & HI_MASK);
    const float r2b = r1b - __builtin_bit_cast(float, c1b & HI_MASK);
    q2 = (__builtin_bit_cast(uint, r2a) >> 16) |
         (__builtin_bit_cast(uint, r2b) & HI_MASK);
}

// ---------------------------------------------------------------------------
// Fused kernel. Grid (16,16) = 256 blocks = 1/CU; block = 1024 threads
// (16 waves, 4/SIMD). Phase 1 (once): transcode this m's codebook slice
// into LDS bf16x3 fragments (96 KB) + c2 (prep's exact summation order).
// ONE __syncthreads. Phase 2: wave w free-runs over rows [rowB+w*32, +32)
// = 2 row-tiles of 16 rows sharing every B batch, sweeping codes in 4
// quarter-passes of 64; per-lane argmin carry; one 4-level lane tree;
// float4-vectorized gather epilogue.
// ---------------------------------------------------------------------------
__global__ __launch_bounds__(1024, 4) void fq_fused_kernel(
        const float* __restrict__ inputs,
        const float* __restrict__ codebook,
        float* __restrict__ out_codes,
        float* __restrict__ out_idx) {
    const int m    = blockIdx.y;
    const int rowB = blockIdx.x * RPB;
    const int w    = (int)threadIdx.x >> 6;
    const int lane = (int)threadIdx.x & 63;
    const int quad = lane >> 4;
    const int col  = lane & 15;

    __shared__ unsigned short lds_b[96 * 512];   // 96 KB: 96 frags x 64 lanes x 8
    __shared__ float s_c2v[NQ];

    // ---- transcode codebook slice into LDS fragments + c2 (once) ----
    // item (n, kc): n = item>>3, kc = item&7 (kc == lane&7 -> the 8-lane
    // shfl tree reproduces the original prep kernel's c2 order exactly).
    const float* cbm = codebook + (size_t)m * NQ * CQ;
    #pragma unroll
    for (int it = 0; it < 2; ++it) {
        const int item = (int)threadIdx.x + it * 1024;
        const int kc = item & 7;
        const int n  = item >> 3;
        const int nt = n >> 4, cc = n & 15;
        const int h = kc >> 2, q = kc & 3;
        const float* src = cbm + (size_t)n * CQ + kc * 8;
        const float4 va = *(const float4*)src;
        const float4 vb = *(const float4*)(src + 4);
        const float el[8] = {va.x, va.y, va.z, va.w, vb.x, vb.y, vb.z, vb.w};

        float s = 0.0f;
        #pragma unroll
        for (int u = 0; u < 8; ++u) s = fmaf(el[u], el[u], s);
        s += __shfl_xor(s, 1, 64);
        s += __shfl_xor(s, 2, 64);
        s += __shfl_xor(s, 4, 64);
        if (kc == 0) s_c2v[n] = s;

        uint p0[4], p1[4], p2[4];
        #pragma unroll
        for (int u = 0; u < 4; ++u)
            split3_pair(el[2 * u], el[2 * u + 1], p0[u], p1[u], p2[u]);
        const int lf = q * 16 + cc;
        #pragma unroll
        for (int j = 0; j < 3; ++j) {
            const uint* p = (j == 0) ? p0 : (j == 1) ? p1 : p2;
            unsigned short* dst =
                &lds_b[(((j << 1) + h) * 16 + nt) * 512 + lf * 8];
            *(uint4*)dst = make_uint4(p[0], p[1], p[2], p[3]);
        }
    }
    __syncthreads();   // the ONLY barrier: B fragments + c2 ready

    // ---- free-running per-wave main: 32 rows (2 rt) x 256 codes ----
    const int row0 = rowB + w * 32;

    // A-fragments for BOTH row-tiles: direct per-lane global reads.
    // Lane (quad,col) reads x[row0+rt*16+col][h*32+quad*8 .. +8]; the 8
    // lanes sharing a row jointly consume the full 256B row -> every 64B
    // line fully used, no fetch amplification.
    shortx8 afr[3][2][2];   // [i][rt][h]
    #pragma unroll
    for (int rt = 0; rt < 2; ++rt) {
        const float* xb =
            inputs + ((size_t)(row0 + rt * 16 + col) * MQ + m) * CQ;
        #pragma unroll
        for (int h = 0; h < 2; ++h) {
            const float4 va = *(const float4*)(xb + h * 32 + quad * 8);
            const float4 vb = *(const float4*)(xb + h * 32 + quad * 8 + 4);
            const float el[8] = {va.x, va.y, va.z, va.w,
                                 vb.x, vb.y, vb.z, vb.w};
            uint q0[4], q1[4], q2[4];
            #pragma unroll
            for (int u = 0; u < 4; ++u)
                split3_pair(el[2 * u], el[2 * u + 1], q0[u], q1[u], q2[u]);
            afr[0][rt][h] = __builtin_bit_cast(shortx8,
                make_uint4(q0[0], q0[1], q0[2], q0[3]));
            afr[1][rt][h] = __builtin_bit_cast(shortx8,
                make_uint4(q1[0], q1[1], q1[2], q1[3]));
            afr[2][rt][h] = __builtin_bit_cast(shortx8,
                make_uint4(q2[0], q2[1], q2[2], q2[3]));
        }
    }

    // per-lane argmin carry (candidates ascend in n -> strict < keeps
    // the lowest n on ties)
    float bdc[2][4]; int bic[2][4];
    #pragma unroll
    for (int rt = 0; rt < 2; ++rt)
        #pragma unroll
        for (int reg = 0; reg < 4; ++reg) { bdc[rt][reg] = FLT_MAX; bic[rt][reg] = 0; }

    // ---- 4 code-quarter passes: 64 codes each ----
    #pragma unroll 1
    for (int cq = 0; cq < 4; ++cq) {
        float c2r[4];
        #pragma unroll
        for (int nt = 0; nt < 4; ++nt)
            c2r[nt] = s_c2v[cq * 64 + nt * 16 + col];

        f32x4 acc[2][4];
        #pragma unroll
        for (int rt = 0; rt < 2; ++rt)
            #pragma unroll
            for (int nt = 0; nt < 4; ++nt)
                acc[rt][nt] = (f32x4){0.f, 0.f, 0.f, 0.f};

        // hot loop: each B batch (4 ds_read_b128) feeds BOTH row-tiles
        #pragma unroll
        for (int h = 0; h < 2; ++h) {
            #pragma unroll
            for (int j = 0; j < 3; ++j) {
                shortx8 bfr[4];
                #pragma unroll
                for (int nt = 0; nt < 4; ++nt)
                    bfr[nt] = *(const shortx8*)
                        &lds_b[(((j << 1) + h) * 16 + cq * 4 + nt) * 512
                               + lane * 8];
                __builtin_amdgcn_s_setprio(1);
                #pragma unroll
                for (int i = 0; i <= 2 - j; ++i) {
                    #pragma unroll
                    for (int nt = 0; nt < 4; ++nt) {
                        acc[0][nt] = __builtin_amdgcn_mfma_f32_16x16x32_bf16(
                            afr[i][0][h], bfr[nt], acc[0][nt], 0, 0, 0);
                        acc[1][nt] = __builtin_amdgcn_mfma_f32_16x16x32_bf16(
                            afr[i][1][h], bfr[nt], acc[1][nt], 0, 0, 0);
                    }
                }
                __builtin_amdgcn_s_setprio(0);
            }
        }

        // per-lane local argmin update (no shuffles here)
        #pragma unroll
        for (int rt = 0; rt < 2; ++rt)
            #pragma unroll
            for (int reg = 0; reg < 4; ++reg)
                #pragma unroll
                for (int nt = 0; nt < 4; ++nt) {
                    const float d = fmaf(-2.0f, acc[rt][nt][reg], c2r[nt]);
                    if (d < bdc[rt][reg]) {
                        bdc[rt][reg] = d;
                        bic[rt][reg] = cq * 64 + nt * 16 + col;
                    }
                }
    }

    // ---- final argmin: 4-level tree over the 16 col lanes (once) ----
    // afterwards every lane of quad q holds the winner of rows
    // rt*16 + q*4 + reg for all reg.
    #pragma unroll
    for (int rt = 0; rt < 2; ++rt)
        #pragma unroll
        for (int reg = 0; reg < 4; ++reg) {
            float bd = bdc[rt][reg]; int bi = bic[rt][reg];
            #pragma unroll
            for (int mask = 1; mask <= 8; mask <<= 1) {
                const float od = __shfl_xor(bd, mask, 64);
                const int   oi = __shfl_xor(bi, mask, 64);
                if (od < bd || (od == bd && oi < bi)) { bd = od; bi = oi; }
            }
            bdc[rt][reg] = bd; bic[rt][reg] = bi;
        }

    // idx write: lane (quad, col==0) owns rows rt*16 + quad*4 + reg
    if (col == 0) {
        #pragma unroll
        for (int rt = 0; rt < 2; ++rt)
            #pragma unroll
            for (int reg = 0; reg < 4; ++reg)
                out_idx[(size_t)(row0 + rt * 16 + quad * 4 + reg) * MQ + m] =
                    (float)bic[rt][reg];
    }

    // ---- gather codes, float4-vectorized: 4 rows per wave-instruction ----
    // dest lane (group g=quad, col) handles row r = jjg*4 + g, element
    // col*4..+3. Winner bic[rt][r&3] lives on quad q_src=(r&15)>>2; each
    // source lane publishes bic[rt][col&3] (static selects), so
    // srcLane = q_src*16 + g delivers bic[rt][g] == bic[rt][r&3].
    {
        const int c2b = col & 3;
        const int cc4 = col * 4;
        #pragma unroll
        for (int jjg = 0; jjg < 8; ++jjg) {
            const int rt = jjg >> 2;
            const int r  = jjg * 4 + quad;
            const int s01 = (c2b & 1) ? bic[rt][1] : bic[rt][0];
            const int s23 = (c2b & 1) ? bic[rt][3] : bic[rt][2];
            const int sel = (c2b & 2) ? s23 : s01;
            const int bn  = __shfl(sel, (jjg & 3) * 16 + quad, 64);
            const float4 cv = *(const float4*)(cbm + (size_t)bn * CQ + cc4);
            *(float4*)(out_codes + ((size_t)(row0 + r) * MQ + m) * CQ + cc4) = cv;
        }
    }
}

extern "C" void kernel_launch(void* const* d_in, const int* in_sizes, int n_in,
                              void* d_out, int out_size, void* d_ws, size_t ws_size,
                              hipStream_t stream) {
    const float* inputs   = (const float*)d_in[0];   // [B, M, C]
    const float* codebook = (const float*)d_in[1];   // [M, N, C]
    float* out_codes = (float*)d_out;                        // [B, M, C]
    float* out_idx   = (float*)d_out + (size_t)BQ * MQ * CQ; // [B, M]
    (void)d_ws; (void)ws_size;

    fq_fused_kernel<<<dim3(BQ / RPB, MQ), 1024, 0, stream>>>(
        inputs, codebook, out_codes, out_idx);
}

// Round 11
// 105.116 us; speedup vs baseline: 1.2093x; 1.2093x over previous
//
#include <hip/hip_runtime.h>
#include <hip/hip_bf16.h>
#include <float.h>

// FactoredQuantizer: B=8192, M=16, N=256, C=64
// inputs  [B, M, C] fp32;  codebook [M, N, C] fp32
// out = codes [B, M, C] fp32 ++ idx [B, M] (as fp32 values)
//
// Round 20: exact revert to round-17 (best measured total: 105.0 us) plus
// ONE codegen-hygiene change. r18/r19 both carried a spill signature
// (WRITE +14 MB, LDS +32 KB = 32 B/thread alloca promoted to LDS, VGPR
// squeezed to 64) that my intended changes didn't explain -> the suspect
// is the per-thread float el[8]/uint p[4] local arrays (exact 32 B match).
// This round: r17 structure verbatim (scalar gather, post-barrier A-build,
// quarter-pass argmin, ONE barrier, setprio) with every local array
// replaced by named scalars / float4 components. FP op order identical
// element-for-element (c2 chain, split order, MFMA chains, tie rules) ->
// bit-identical output.

#define BQ 8192
#define MQ 16
#define NQ 256
#define CQ 64
#define RPB 512       // rows per block (16 waves x 32 rows)

typedef short  shortx8 __attribute__((ext_vector_type(8)));
typedef float  f32x4   __attribute__((ext_vector_type(4)));

#define HI_MASK 0xffff0000u

// Truncation 3-split of two floats a,b packed into three dwords
// (low short = a's bf16, high short = b's bf16). Exact: a0+a1+a2 == a.
__device__ __forceinline__ void split3_pair(float a, float b,
                                            uint& q0, uint& q1, uint& q2) {
    const uint ba = __builtin_bit_cast(uint, a);
    const uint bb = __builtin_bit_cast(uint, b);
    q0 = (ba >> 16) | (bb & HI_MASK);
    const float r1a = a - __builtin_bit_cast(float, ba & HI_MASK);
    const float r1b = b - __builtin_bit_cast(float, bb & HI_MASK);
    const uint c1a = __builtin_bit_cast(uint, r1a);
    const uint c1b = __builtin_bit_cast(uint, r1b);
    q1 = (c1a >> 16) | (c1b & HI_MASK);
    const float r2a = r1a - __builtin_bit_cast(float, c1a & HI_MASK);
    const float r2b = r1b - __builtin_bit_cast(float, c1b & HI_MASK);
    q2 = (__builtin_bit_cast(uint, r2a) >> 16) |
         (__builtin_bit_cast(uint, r2b) & HI_MASK);
}

// ---------------------------------------------------------------------------
// Fused kernel. Grid (16,16) = 256 blocks = 1/CU; block = 1024 threads
// (16 waves, 4/SIMD). Phase 1 (once): transcode this m's codebook slice
// into LDS bf16x3 fragments (96 KB) + c2 (prep's exact summation order).
// ONE __syncthreads. Phase 2: wave w free-runs over rows [rowB+w*32, +32)
// = 2 row-tiles of 16 rows sharing every B batch, sweeping codes in 4
// quarter-passes of 64; per-lane argmin carry; one 4-level lane tree;
// scalar gather epilogue (r17's — the vectorized one regressed).
// ---------------------------------------------------------------------------
__global__ __launch_bounds__(1024, 4) void fq_fused_kernel(
        const float* __restrict__ inputs,
        const float* __restrict__ codebook,
        float* __restrict__ out_codes,
        float* __restrict__ out_idx) {
    const int m    = blockIdx.y;
    const int rowB = blockIdx.x * RPB;
    const int w    = (int)threadIdx.x >> 6;
    const int lane = (int)threadIdx.x & 63;
    const int quad = lane >> 4;
    const int col  = lane & 15;

    __shared__ unsigned short lds_b[96 * 512];   // 96 KB: 96 frags x 64 lanes x 8
    __shared__ float s_c2v[NQ];

    // ---- transcode codebook slice into LDS fragments + c2 (once) ----
    // item (n, kc): n = item>>3, kc = item&7 (kc == lane&7 -> the 8-lane
    // shfl tree reproduces the original prep kernel's c2 order exactly).
    const float* cbm = codebook + (size_t)m * NQ * CQ;
    #pragma unroll
    for (int it = 0; it < 2; ++it) {
        const int item = (int)threadIdx.x + it * 1024;
        const int kc = item & 7;
        const int n  = item >> 3;
        const int nt = n >> 4, cc = n & 15;
        const int h = kc >> 2, q = kc & 3;
        const float* src = cbm + (size_t)n * CQ + kc * 8;
        const float4 va = *(const float4*)src;
        const float4 vb = *(const float4*)(src + 4);

        // c2 partial: same chain order as el[0..7]
        float s = 0.0f;
        s = fmaf(va.x, va.x, s); s = fmaf(va.y, va.y, s);
        s = fmaf(va.z, va.z, s); s = fmaf(va.w, va.w, s);
        s = fmaf(vb.x, vb.x, s); s = fmaf(vb.y, vb.y, s);
        s = fmaf(vb.z, vb.z, s); s = fmaf(vb.w, vb.w, s);
        s += __shfl_xor(s, 1, 64);
        s += __shfl_xor(s, 2, 64);
        s += __shfl_xor(s, 4, 64);
        if (kc == 0) s_c2v[n] = s;

        // 3-way truncation split into named uint4s (no local arrays)
        uint4 P0, P1, P2;
        split3_pair(va.x, va.y, P0.x, P1.x, P2.x);
        split3_pair(va.z, va.w, P0.y, P1.y, P2.y);
        split3_pair(vb.x, vb.y, P0.z, P1.z, P2.z);
        split3_pair(vb.z, vb.w, P0.w, P1.w, P2.w);

        const int lf = q * 16 + cc;
        unsigned short* dst0 = &lds_b[((0 + h) * 16 + nt) * 512 + lf * 8];
        unsigned short* dst1 = &lds_b[((2 + h) * 16 + nt) * 512 + lf * 8];
        unsigned short* dst2 = &lds_b[((4 + h) * 16 + nt) * 512 + lf * 8];
        *(uint4*)dst0 = P0;
        *(uint4*)dst1 = P1;
        *(uint4*)dst2 = P2;
    }
    __syncthreads();   // the ONLY barrier: B fragments + c2 ready

    // ---- free-running per-wave main: 32 rows (2 rt) x 256 codes ----
    const int row0 = rowB + w * 32;

    // A-fragments for BOTH row-tiles: direct per-lane global reads.
    // Lane (quad,col) reads x[row0+rt*16+col][h*32+quad*8 .. +8]; the 8
    // lanes sharing a row jointly consume the full 256B row -> every 64B
    // line fully used, no fetch amplification.
    shortx8 afr[3][2][2];   // [i][rt][h]
    #pragma unroll
    for (int rt = 0; rt < 2; ++rt) {
        const float* xb =
            inputs + ((size_t)(row0 + rt * 16 + col) * MQ + m) * CQ;
        #pragma unroll
        for (int h = 0; h < 2; ++h) {
            const float4 va = *(const float4*)(xb + h * 32 + quad * 8);
            const float4 vb = *(const float4*)(xb + h * 32 + quad * 8 + 4);
            uint4 Q0, Q1, Q2;
            split3_pair(va.x, va.y, Q0.x, Q1.x, Q2.x);
            split3_pair(va.z, va.w, Q0.y, Q1.y, Q2.y);
            split3_pair(vb.x, vb.y, Q0.z, Q1.z, Q2.z);
            split3_pair(vb.z, vb.w, Q0.w, Q1.w, Q2.w);
            afr[0][rt][h] = __builtin_bit_cast(shortx8, Q0);
            afr[1][rt][h] = __builtin_bit_cast(shortx8, Q1);
            afr[2][rt][h] = __builtin_bit_cast(shortx8, Q2);
        }
    }

    // per-lane argmin carry (candidates ascend in n -> strict < keeps
    // the lowest n on ties)
    float bdc[2][4]; int bic[2][4];
    #pragma unroll
    for (int rt = 0; rt < 2; ++rt)
        #pragma unroll
        for (int reg = 0; reg < 4; ++reg) { bdc[rt][reg] = FLT_MAX; bic[rt][reg] = 0; }

    // ---- 4 code-quarter passes: 64 codes each ----
    #pragma unroll 1
    for (int cq = 0; cq < 4; ++cq) {
        float c2r[4];
        #pragma unroll
        for (int nt = 0; nt < 4; ++nt)
            c2r[nt] = s_c2v[cq * 64 + nt * 16 + col];

        f32x4 acc[2][4];
        #pragma unroll
        for (int rt = 0; rt < 2; ++rt)
            #pragma unroll
            for (int nt = 0; nt < 4; ++nt)
                acc[rt][nt] = (f32x4){0.f, 0.f, 0.f, 0.f};

        // hot loop: each B batch (4 ds_read_b128) feeds BOTH row-tiles
        #pragma unroll
        for (int h = 0; h < 2; ++h) {
            #pragma unroll
            for (int j = 0; j < 3; ++j) {
                shortx8 bfr[4];
                #pragma unroll
                for (int nt = 0; nt < 4; ++nt)
                    bfr[nt] = *(const shortx8*)
                        &lds_b[(((j << 1) + h) * 16 + cq * 4 + nt) * 512
                               + lane * 8];
                __builtin_amdgcn_s_setprio(1);
                #pragma unroll
                for (int i = 0; i <= 2 - j; ++i) {
                    #pragma unroll
                    for (int nt = 0; nt < 4; ++nt) {
                        acc[0][nt] = __builtin_amdgcn_mfma_f32_16x16x32_bf16(
                            afr[i][0][h], bfr[nt], acc[0][nt], 0, 0, 0);
                        acc[1][nt] = __builtin_amdgcn_mfma_f32_16x16x32_bf16(
                            afr[i][1][h], bfr[nt], acc[1][nt], 0, 0, 0);
                    }
                }
                __builtin_amdgcn_s_setprio(0);
            }
        }

        // per-lane local argmin update (no shuffles here)
        #pragma unroll
        for (int rt = 0; rt < 2; ++rt)
            #pragma unroll
            for (int reg = 0; reg < 4; ++reg)
                #pragma unroll
                for (int nt = 0; nt < 4; ++nt) {
                    const float d = fmaf(-2.0f, acc[rt][nt][reg], c2r[nt]);
                    if (d < bdc[rt][reg]) {
                        bdc[rt][reg] = d;
                        bic[rt][reg] = cq * 64 + nt * 16 + col;
                    }
                }
    }

    // ---- final argmin: 4-level tree over the 16 col lanes (once) ----
    // afterwards every lane of quad q holds the winner of rows
    // rt*16 + q*4 + reg for all reg.
    #pragma unroll
    for (int rt = 0; rt < 2; ++rt)
        #pragma unroll
        for (int reg = 0; reg < 4; ++reg) {
            float bd = bdc[rt][reg]; int bi = bic[rt][reg];
            #pragma unroll
            for (int mask = 1; mask <= 8; mask <<= 1) {
                const float od = __shfl_xor(bd, mask, 64);
                const int   oi = __shfl_xor(bi, mask, 64);
                if (od < bd || (od == bd && oi < bi)) { bd = od; bi = oi; }
            }
            bdc[rt][reg] = bd; bic[rt][reg] = bi;
        }

    // idx write: lane (quad, col==0) owns rows rt*16 + quad*4 + reg
    if (col == 0) {
        #pragma unroll
        for (int rt = 0; rt < 2; ++rt)
            #pragma unroll
            for (int reg = 0; reg < 4; ++reg)
                out_idx[(size_t)(row0 + rt * 16 + quad * 4 + reg) * MQ + m] =
                    (float)bic[rt][reg];
    }

    // gather codes: row jj's winner lives on lane ((jj&15)>>2)*16, reg jj&3
    // of tile jj>>4; lane = element (256B stores)
    #pragma unroll
    for (int jj = 0; jj < 32; ++jj) {
        const int rt  = jj >> 4;
        const int r16 = jj & 15;
        const int bn  = __shfl(bic[rt][r16 & 3], (r16 >> 2) * 16, 64);
        out_codes[((size_t)(row0 + jj) * MQ + m) * CQ + lane] =
            cbm[(size_t)bn * CQ + lane];
    }
}

extern "C" void kernel_launch(void* const* d_in, const int* in_sizes, int n_in,
                              void* d_out, int out_size, void* d_ws, size_t ws_size,
                              hipStream_t stream) {
    const float* inputs   = (const float*)d_in[0];   // [B, M, C]
    const float* codebook = (const float*)d_in[1];   // [M, N, C]
    float* out_codes = (float*)d_out;                        // [B, M, C]
    float* out_idx   = (float*)d_out + (size_t)BQ * MQ * CQ; // [B, M]
    (void)d_ws; (void)ws_size;

    fq_fused_kernel<<<dim3(BQ / RPB, MQ), 1024, 0, stream>>>(
        inputs, codebook, out_codes, out_idx);
}